// Round 9
// baseline (136.132 us; speedup 1.0000x reference)
//
#include <hip/hip_runtime.h>
#include <hip/hip_bf16.h>
#include <stdint.h>

typedef unsigned short u16;
typedef __attribute__((ext_vector_type(8))) short short8;
typedef __attribute__((ext_vector_type(4))) float f32x4;

// ---------- helpers ----------
__device__ __forceinline__ uint32_t f2bf(float f) {
    union { float f; uint32_t u; } c; c.f = f;
    uint32_t u = c.u;
    u += 0x7fffu + ((u >> 16) & 1u);   // round-to-nearest-even
    return u >> 16;
}

__device__ __forceinline__ void glds16(const void* g, void* l) {
    __builtin_amdgcn_global_load_lds(
        (const __attribute__((address_space(1))) uint32_t*)g,
        (__attribute__((address_space(3))) uint32_t*)l,
        16, 0, 0);
}

__device__ __forceinline__ uint2 wrow2(float4 wi, float4 pp, float4 gv) {
    uint32_t lo = f2bf(wi.x + pp.x * gv.x) | (f2bf(wi.y + pp.y * gv.y) << 16);
    uint32_t hi = f2bf(wi.z + pp.z * gv.z) | (f2bf(wi.w + pp.w * gv.w) << 16);
    return make_uint2(lo, hi);
}

// ---------- kernel 1: g_p = FWHT_1024(D_p[:1024] * V) / 1024, for 4 params ----------
__global__ void fwht_g_kernel(const float* __restrict__ V,
                              const float* __restrict__ D0, const float* __restrict__ D1,
                              const float* __restrict__ D2, const float* __restrict__ D3,
                              float* __restrict__ g) {
    __shared__ float s[1024];
    int t = threadIdx.x;
    const float* D = (blockIdx.x == 0) ? D0 : (blockIdx.x == 1) ? D1 :
                     (blockIdx.x == 2) ? D2 : D3;
    s[t] = D[t] * V[t];
    __syncthreads();
    #pragma unroll
    for (int st = 512; st >= 1; st >>= 1) {
        float a = s[t];
        float b = s[t ^ st];
        __syncthreads();
        s[t] = (t & st) ? (b - a) : (a + b);
        __syncthreads();
    }
    g[blockIdx.x * 1024 + t] = s[t] * (1.0f / 1024.0f);
}

// ---------- kernel 2: bias = init + PP * g[i&1023] ----------
__global__ void bias_kernel(const float* __restrict__ init, const float* __restrict__ PP,
                            const float* __restrict__ g, float* __restrict__ out, int n) {
    int i = blockIdx.x * blockDim.x + threadIdx.x;
    if (i < n) out[i] = init[i] + PP[i] * g[i & 1023];
}

// ---------- kernel 3: f32 -> bf16 cast (x), 4 elems/thread ----------
__global__ void cast_kernel(const float* __restrict__ in, u16* __restrict__ out, int n4) {
    int i = blockIdx.x * blockDim.x + threadIdx.x;
    if (i >= n4) return;
    float4 v = ((const float4*)in)[i];
    uint32_t lo = f2bf(v.x) | (f2bf(v.y) << 16);
    uint32_t hi = f2bf(v.z) | (f2bf(v.w) << 16);
    ((uint2*)out)[i] = make_uint2(lo, hi);
}

// ---------- kernel 4: fused W-gen + split-K GEMM, v6 (TLP-first) ----------
// BM=128, BN=64, BK=64, single-buffered LDS (24 KB) -> high blocks/CU.
// Grid (64 bn, 4 bm, 4 sk) = 1024 WGs = 4+/CU resident (the TLP fix).
// Depth-1 W prefetch in named regs crosses the barrier via counted vmcnt(8).
// XOR swizzle on both LDS tiles (validated round 8).
// 4 waves in 2x2: wave tile 64 rows x 32 cols, acc[4][2] (16 MFMA/wave/step).
__global__ __launch_bounds__(256, 4) void gemm_fused(const u16* __restrict__ A,
                                                     const float* __restrict__ Winit,
                                                     const float* __restrict__ PP,
                                                     const float* __restrict__ gvec,
                                                     float* __restrict__ P,
                                                     int M, int N, int K, int Kslice) {
    constexpr int BM = 128, BN = 64, BK = 64;
    __shared__ u16 As[BM * BK];   // 16 KB
    __shared__ u16 Bs[BN * BK];   // 8 KB   -> 24 KB total

    const int t    = threadIdx.x;
    const int wid  = t >> 6;
    const int lane = t & 63;
    const int wr   = wid >> 1;        // 0..1: 64-row block
    const int wc   = wid & 1;         // 0..1: 32-col block
    const int fr   = lane & 15;
    const int fq   = lane >> 4;
    const int rx   = (fr & 7) << 4;   // read-side swizzle xor (bytes)

    const int bn = blockIdx.x, bm = blockIdx.y, sk = blockIdx.z;
    const int k_beg = sk * Kslice;
    const int nstep = Kslice / BK;

    const u16* Abase = A + (size_t)(bm * BM) * K;

    // W-gen mapping: thread covers W rows rB+{0,16,32,48}, k-cols cB..cB+3
    const int rB  = t >> 4;           // 0..15
    const int cB  = (t & 15) * 4;     // f32 col
    const int cb8 = (t & 15) * 8;     // byte col in Bs row
    const int wxor = (rB & 7) << 4;   // write-side swizzle xor
    const float* Wb = Winit + (size_t)(bn * BN + rB) * K;
    const float* Pb = PP    + (size_t)(bn * BN + rB) * K;
    const size_t rstride = (size_t)16 * K;

    float4 wi0, wi1, wi2, wi3, pp0, pp1, pp2, pp3;   // named -> never spilled

#define PF_W(k0) do {                                         \
        const float* wp_ = Wb + (k0) + cB;                    \
        const float* qp_ = Pb + (k0) + cB;                    \
        wi0 = *(const float4*)(wp_);                          \
        wi1 = *(const float4*)(wp_ + rstride);                \
        wi2 = *(const float4*)(wp_ + 2 * rstride);            \
        wi3 = *(const float4*)(wp_ + 3 * rstride);            \
        pp0 = *(const float4*)(qp_);                          \
        pp1 = *(const float4*)(qp_ + rstride);                \
        pp2 = *(const float4*)(qp_ + 2 * rstride);            \
        pp3 = *(const float4*)(qp_ + 3 * rstride);            \
    } while (0)

// swizzled B write: byte (row*128 + cb8) ^ ((row&7)<<4); row&7 == rB&7
#define WRITE_B(k0) do {                                                          \
        float4 gv_ = *(const float4*)(gvec + (((k0) + cB) & 1023));               \
        char* Bp_ = (char*)Bs;                                                    \
        *(uint2*)(Bp_ + ((((rB +  0) * 128 + cb8)) ^ wxor)) = wrow2(wi0, pp0, gv_); \
        *(uint2*)(Bp_ + ((((rB + 16) * 128 + cb8)) ^ wxor)) = wrow2(wi1, pp1, gv_); \
        *(uint2*)(Bp_ + ((((rB + 32) * 128 + cb8)) ^ wxor)) = wrow2(wi2, pp2, gv_); \
        *(uint2*)(Bp_ + ((((rB + 48) * 128 + cb8)) ^ wxor)) = wrow2(wi3, pp3, gv_); \
    } while (0)

// As staging: LDS dest linear (glds requirement); SOURCE col-group pre-swizzled
#define STAGE_A(k0) do {                                                          \
        _Pragma("unroll")                                                         \
        for (int q_ = 0; q_ < 4; ++q_) {                                          \
            int L_ = q_ * 256 + t;                 /* 16B chunk index */          \
            int row_ = L_ >> 3;                                                   \
            int cg_ = (L_ & 7) ^ (row_ & 7);       /* swizzled src col16 */       \
            glds16(Abase + (size_t)row_ * K + (k0) + cg_ * 8, As + L_ * 8);       \
        }                                                                         \
    } while (0)

#define MFMA_STEP() do {                                                          \
        const char* Ap_ = (const char*)As;                                        \
        const char* Bp_ = (const char*)Bs;                                        \
        __builtin_amdgcn_s_setprio(1);                                            \
        _Pragma("unroll")                                                         \
        for (int ks_ = 0; ks_ < 2; ++ks_) {                                       \
            const int co_ = (ks_ * 64 + fq * 16) ^ rx;                            \
            short8 a_[4], b_[2];                                                  \
            _Pragma("unroll")                                                     \
            for (int m_ = 0; m_ < 4; ++m_)                                        \
                a_[m_] = *(const short8*)(Ap_ +                                   \
                          (wr * 64 + m_ * 16 + fr) * 128 + co_);                  \
            _Pragma("unroll")                                                     \
            for (int n_ = 0; n_ < 2; ++n_)                                        \
                b_[n_] = *(const short8*)(Bp_ +                                   \
                          (wc * 32 + n_ * 16 + fr) * 128 + co_);                  \
            _Pragma("unroll")                                                     \
            for (int m_ = 0; m_ < 4; ++m_)                                        \
                _Pragma("unroll")                                                 \
                for (int n_ = 0; n_ < 2; ++n_)                                    \
                    acc[m_][n_] = __builtin_amdgcn_mfma_f32_16x16x32_bf16(        \
                        a_[m_], b_[n_], acc[m_][n_], 0, 0, 0);                    \
        }                                                                         \
        __builtin_amdgcn_s_setprio(0);                                            \
    } while (0)

    f32x4 acc[4][2];
    #pragma unroll
    for (int m = 0; m < 4; ++m)
        #pragma unroll
        for (int n = 0; n < 2; ++n)
            acc[m][n] = (f32x4){0.f, 0.f, 0.f, 0.f};

    // ---- depth-1 W prologue ----
    PF_W(k_beg);
    __builtin_amdgcn_sched_barrier(0);

    #pragma unroll 1
    for (int s = 0; s < nstep; ++s) {
        const int k0 = k_beg + s * BK;
        const int kn = (s + 1 < nstep) ? (k0 + BK) : k_beg;   // clamped tail reload

        STAGE_A(k0);                    // 4 glds (newest)
        __builtin_amdgcn_sched_barrier(0);
        WRITE_B(k0);                    // auto vmcnt(4): waits W(s), glds fly
        __builtin_amdgcn_sched_barrier(0);
        PF_W(kn);                       // W(s+1): stays in flight across barrier
        __builtin_amdgcn_sched_barrier(0);
        asm volatile("s_waitcnt vmcnt(8) lgkmcnt(0)" ::: "memory");  // drain glds+ds_write, keep 8 W
        __builtin_amdgcn_s_barrier();
        __builtin_amdgcn_sched_barrier(0);
        MFMA_STEP();
        __builtin_amdgcn_sched_barrier(0);
        __builtin_amdgcn_s_barrier();   // protect LDS before next stage
        __builtin_amdgcn_sched_barrier(0);
    }

#undef PF_W
#undef WRITE_B
#undef STAGE_A
#undef MFMA_STEP

    // epilogue: write f32 partial tile
    float* Pp = P + (size_t)sk * M * N;
    #pragma unroll
    for (int m = 0; m < 4; ++m) {
        int grow0 = bm * BM + wr * 64 + m * 16 + fq * 4;
        #pragma unroll
        for (int n = 0; n < 2; ++n) {
            int gcol = bn * BN + wc * 32 + n * 16 + fr;
            #pragma unroll
            for (int j = 0; j < 4; ++j)
                Pp[(size_t)(grow0 + j) * N + gcol] = acc[m][n][j];
        }
    }
}

// ---------- kernel 5: reduce S partials + bias (+relu) -> bf16 or f32 ----------
template <typename OutT, bool RELU, int S>
__global__ void reduce_kernel(const float* __restrict__ P, const float* __restrict__ bias,
                              OutT* __restrict__ out, int MN, int N) {
    int i = blockIdx.x * blockDim.x + threadIdx.x;   // handles 4 elems
    if (i * 4 >= MN) return;
    int e = i * 4;
    int col = e & (N - 1);
    float4 acc = ((const float4*)(P + e))[0];
    #pragma unroll
    for (int s = 1; s < S; ++s) {
        float4 p = ((const float4*)(P + (size_t)s * MN + e))[0];
        acc.x += p.x; acc.y += p.y; acc.z += p.z; acc.w += p.w;
    }
    float4 bv = *((const float4*)(bias + col));
    acc.x += bv.x; acc.y += bv.y; acc.z += bv.z; acc.w += bv.w;
    if (RELU) {
        acc.x = fmaxf(acc.x, 0.f); acc.y = fmaxf(acc.y, 0.f);
        acc.z = fmaxf(acc.z, 0.f); acc.w = fmaxf(acc.w, 0.f);
    }
    if constexpr (sizeof(OutT) == 2) {
        uint32_t lo = f2bf(acc.x) | (f2bf(acc.y) << 16);
        uint32_t hi = f2bf(acc.z) | (f2bf(acc.w) << 16);
        ((uint2*)out)[i] = make_uint2(lo, hi);
    } else {
        ((float4*)out)[i] = acc;
    }
}

// ---------- launch ----------
extern "C" void kernel_launch(void* const* d_in, const int* in_sizes, int n_in,
                              void* d_out, int out_size, void* d_ws, size_t ws_size,
                              hipStream_t stream) {
    (void)in_sizes; (void)n_in; (void)out_size; (void)ws_size;

    const float* x       = (const float*)d_in[0];
    const float* V       = (const float*)d_in[1];
    const float* W1_init = (const float*)d_in[2];
    const float* D_W1    = (const float*)d_in[3];
    const float* PP_W1   = (const float*)d_in[4];
    const float* b1_init = (const float*)d_in[5];
    const float* D_b1    = (const float*)d_in[6];
    const float* PP_b1   = (const float*)d_in[7];
    const float* W2_init = (const float*)d_in[8];
    const float* D_W2    = (const float*)d_in[9];
    const float* PP_W2   = (const float*)d_in[10];
    const float* b2_init = (const float*)d_in[11];
    const float* D_b2    = (const float*)d_in[12];
    const float* PP_b2   = (const float*)d_in[13];

    constexpr size_t MB = 1024 * 1024;
    char* ws = (char*)d_ws;
    float* g    = (float*)(ws);                      // 4x1024 f32: [W1 | b1 | W2 | b2]
    float* b1w  = (float*)(ws + 16384);              // 4096 f32
    float* b2w  = (float*)(ws + 32768);              // 4096 f32
    u16*   xb   = (u16*)(ws + 65536);                // 512x4096 bf16 (4 MB)
    u16*   hb   = (u16*)(ws + 65536 + 4 * MB);       // 512x4096 bf16 (4 MB)
    float* Pbuf = (float*)(ws + 65536 + 8 * MB);     // 4x512x4096 f32 (32 MB)

    const int M = 512, N = 4096, K = 4096, S = 4, Kslice = K / S;

    fwht_g_kernel<<<4, 1024, 0, stream>>>(V, D_W1, D_b1, D_W2, D_b2, g);
    bias_kernel<<<4, 1024, 0, stream>>>(b1_init, PP_b1, g + 1024, b1w, 4096);
    bias_kernel<<<4, 1024, 0, stream>>>(b2_init, PP_b2, g + 3072, b2w, 4096);
    cast_kernel<<<2048, 256, 0, stream>>>(x, xb, M * K / 4);

    // layer 1: fused W1-gen GEMM (grid 64 x 4 x 4 = 1024 WGs)
    gemm_fused<<<dim3(N / 64, M / 128, S), 256, 0, stream>>>(xb, W1_init, PP_W1, g, Pbuf, M, N, K, Kslice);
    reduce_kernel<u16, true, S><<<M * N / 4 / 256, 256, 0, stream>>>(Pbuf, b1w, hb, M * N, N);

    // layer 2: fused W2-gen GEMM
    gemm_fused<<<dim3(N / 64, M / 128, S), 256, 0, stream>>>(hb, W2_init, PP_W2, g + 2048, Pbuf, M, N, K, Kslice);
    reduce_kernel<float, false, S><<<M * N / 4 / 256, 256, 0, stream>>>(Pbuf, b2w, (float*)d_out, M * N, N);
}